// Round 6
// baseline (391.721 us; speedup 1.0000x reference)
//
#include <hip/hip_runtime.h>
#include <hip/hip_bf16.h>

#define K_DIM 4096
#define N_DIM 12288
#define B_DIM 64
#define G_DIM 64          // K / 64 groups
#define R_DIM 32
#define NT_DIM 768        // N / 16 n-tiles

typedef int v4i __attribute__((ext_vector_type(4)));

__device__ __forceinline__ int pack4(const v4i a) {
    return (a.x & 255) | ((a.y & 255) << 8) | ((a.z & 255) << 16) | (a.w << 24);
}

// ---------------------------------------------------------------------------
// Kernel 1: fused quantize + lora-down partial.
// Grid = B*16 blocks = (token b, k-chunk kc of 256). 256 threads.
//  - phase A: xd = x/smooth (one value/thread, shared via LDS); per-group
//    (64 consecutive threads = one wave = one group) absmax shuffle-reduce,
//    int4 quantize, write xq in MFMA-lane-packed layout
//    xq_p[bt][g][quad*16+(b&15)][16B]. rintf == jnp.round (half-even).
//  - phase B: lora partial: r = tid&31, c = tid>>5 sums 32 k's from LDS,
//    8->1 LDS reduce, write t_part[kc][b][r]  (disjoint slices -> no atomic,
//    no zero-init needed).
// ---------------------------------------------------------------------------
__global__ __launch_bounds__(256) void quant_lora_kernel(
    const float* __restrict__ x, const float* __restrict__ smooth,
    const float* __restrict__ ld, char* __restrict__ xq_p,
    float* __restrict__ ascale, float* __restrict__ t_part) {
    const int b = blockIdx.x >> 4;
    const int kc = blockIdx.x & 15;
    const int tid = threadIdx.x;
    const int k = kc * 256 + tid;

    __shared__ float sx[256];
    __shared__ float red[256];

    const float xd = x[b * K_DIM + k] / smooth[k];
    sx[tid] = xd;

    // --- quant (wave == group) ---
    const int lane = tid & 63;
    float a = fabsf(xd);
    #pragma unroll
    for (int off = 32; off; off >>= 1) a = fmaxf(a, __shfl_xor(a, off));
    const float as = fmaxf(a / 7.0f, 1e-8f);
    float q = rintf(xd / as);
    q = fminf(fmaxf(q, -8.0f), 7.0f);
    const int g = kc * 4 + (tid >> 6);
    const int bt = b >> 4, b15 = b & 15;
    const int quad = lane >> 4, kin = lane & 15;
    xq_p[((((size_t)bt * G_DIM + g) * 64) + quad * 16 + b15) * 16 + kin] = (char)(int)q;
    if (lane == 0) ascale[b * G_DIM + g] = as;
    __syncthreads();

    // --- lora-down partial over this 256-k chunk ---
    const int r = tid & 31, c = tid >> 5;     // c = 0..7
    const int kb = kc * 256 + c * 32;
    float acc = 0.f;
    #pragma unroll 8
    for (int kk = 0; kk < 32; ++kk)
        acc += sx[c * 32 + kk] * ld[(size_t)(kb + kk) * R_DIM + r];
    red[tid] = acc;
    __syncthreads();
    if (tid < 32) {
        float s = 0.f;
        #pragma unroll
        for (int c2 = 0; c2 < 8; ++c2) s += red[c2 * 32 + tid];
        t_part[kc * (B_DIM * R_DIM) + b * R_DIM + tid] = s;
    }
}

// ---------------------------------------------------------------------------
// Kernel 2: fused main. Grid = 768 blocks (one 16-col n-tile), 4 waves;
// wave w owns b-tile w -> no cross-wave reduction. Exactly 3 blocks/CU.
// K-loop: 8 chunks x 8 groups, double-buffered LDS staging of q_w:
//   staging: thread (srow=t>>4, scol=t&15) reads 8x dwordx4 from q_w row
//   n0+srow (wave: 4x 256 B contiguous segments/instr, every byte used;
//   128 B in flight/thread), packs int32->int8x4, writes LDS rows with
//   80 B stride (bank spans 2-way aliased = free).
//   compute: per group ds_read_b128 bq + coalesced 1 KB/wave xa load (L2)
//   + mfma_i32_16x16x64_i8 + 4 scale-FMAs.
// Loads for chunk j+1 issue before compute(j); pack after; one barrier/chunk.
// Epilogue: sum 16 t_part slices into s_t (one-time), bias + rank-32 lora,
// direct coalesced stores.
// ---------------------------------------------------------------------------
__global__ __launch_bounds__(256) void main_fused_kernel(
    const int* __restrict__ qw, const float* __restrict__ wscales,
    const v4i* __restrict__ xq_p, const float* __restrict__ ascale,
    const float* __restrict__ t_part, const float* __restrict__ lora_up,
    const float* __restrict__ bias, float* __restrict__ out) {
    __shared__ float s_ws[G_DIM * 16];      // [g][j]    4 KB
    __shared__ float s_as[G_DIM * 68];      // [g][b]   17 KB (pad 68)
    __shared__ float s_t[B_DIM * R_DIM];    // [b][r]    8 KB
    __shared__ int   s_qp[2][2560];         // 2 x (8 grp x 16 rows x 80 B)

    const int nt = blockIdx.x;
    const int n0 = nt * 16;
    const int tid = threadIdx.x;

    // staging-role indices
    const int srow = tid >> 4;              // 0..15  (n-row within tile)
    const int scol = tid & 15;              // 0..15  (4-int32 col group)
    const int* gptr = qw + (size_t)(n0 + srow) * K_DIM + scol * 4;
    const int lds_w = srow * 20 + scol;     // int index within a group row blk

    // one-time LDS stages
    for (int i = tid; i < G_DIM * 16; i += 256)
        s_ws[i] = wscales[(i >> 4) * N_DIM + n0 + (i & 15)];
    for (int i = tid; i < B_DIM * G_DIM; i += 256) {
        const int b = i >> 6, g = i & 63;
        s_as[g * 68 + b] = ascale[i];
    }
    for (int i = tid; i < B_DIM * R_DIM; i += 256) {
        float s = 0.f;
        #pragma unroll
        for (int kc = 0; kc < 16; ++kc) s += t_part[kc * (B_DIM * R_DIM) + i];
        s_t[i] = s;
    }

    // stage chunk 0 (groups 0..7)
    {
        v4i qa[8];
        #pragma unroll
        for (int i = 0; i < 8; ++i) qa[i] = *(const v4i*)(gptr + i * 64);
        #pragma unroll
        for (int i = 0; i < 8; ++i) s_qp[0][i * 320 + lds_w] = pack4(qa[i]);
    }
    __syncthreads();

    const int w = tid >> 6, lane = tid & 63;
    const int col = lane & 15, quad = lane >> 4;

    float facc[4] = {0.f, 0.f, 0.f, 0.f};
    const v4i zero = {0, 0, 0, 0};
    const v4i* xbase = xq_p + (size_t)w * G_DIM * 64 + lane;
    const char* rdb0 = (const char*)&s_qp[0][0] + col * 80 + quad * 16;
    const char* rdb1 = (const char*)&s_qp[1][0] + col * 80 + quad * 16;

    #pragma unroll
    for (int j = 0; j < 8; ++j) {
        // issue global loads for chunk j+1 (consumed only in the pack below)
        v4i qa[8];
        if (j < 7) {
            const int* p = gptr + (j + 1) * 512;
            #pragma unroll
            for (int i = 0; i < 8; ++i) qa[i] = *(const v4i*)(p + i * 64);
        }
        // compute chunk j (8 groups)
        const char* rd = (j & 1) ? rdb1 : rdb0;
        #pragma unroll
        for (int gi = 0; gi < 8; ++gi) {
            const int g = j * 8 + gi;
            const v4i bq = *(const v4i*)(rd + gi * 1280);
            const v4i xa = xbase[(size_t)g * 64];
            const v4i d = __builtin_amdgcn_mfma_i32_16x16x64_i8(xa, bq, zero, 0, 0, 0);
            const float wsc = s_ws[g * 16 + col];
            const float4 as4 = *(const float4*)&s_as[g * 68 + w * 16 + quad * 4];
            facc[0] = fmaf(as4.x * wsc, (float)d[0], facc[0]);
            facc[1] = fmaf(as4.y * wsc, (float)d[1], facc[1]);
            facc[2] = fmaf(as4.z * wsc, (float)d[2], facc[2]);
            facc[3] = fmaf(as4.w * wsc, (float)d[3], facc[3]);
        }
        // pack + write chunk j+1 into the other buffer
        if (j < 7) {
            int* wb = (j & 1) ? &s_qp[0][0] : &s_qp[1][0];
            #pragma unroll
            for (int i = 0; i < 8; ++i) wb[i * 320 + lds_w] = pack4(qa[i]);
        }
        __syncthreads();
    }

    // ---- epilogue: bias + rank-32 lora, direct store ----
    const int n = n0 + col;
    float4 lu[8];
    {
        const float4* lp = (const float4*)(lora_up + (size_t)n * R_DIM);
        #pragma unroll
        for (int i = 0; i < 8; ++i) lu[i] = lp[i];
    }
    const float bs = bias[n];
    #pragma unroll
    for (int r = 0; r < 4; ++r) {
        const int b = w * 16 + quad * 4 + r;
        float acc = facc[r] + bs;
        #pragma unroll
        for (int r2 = 0; r2 < 8; ++r2) {
            const float4 tv = *(const float4*)&s_t[b * R_DIM + r2 * 4];
            acc += tv.x * lu[r2].x + tv.y * lu[r2].y +
                   tv.z * lu[r2].z + tv.w * lu[r2].w;
        }
        out[(size_t)b * N_DIM + n] = acc;
    }
}

// ---------------------------------------------------------------------------
extern "C" void kernel_launch(void* const* d_in, const int* in_sizes, int n_in,
                              void* d_out, int out_size, void* d_ws, size_t ws_size,
                              hipStream_t stream) {
    const float* x         = (const float*)d_in[0];
    const int*   q_w       = (const int*)d_in[1];
    const float* wscales   = (const float*)d_in[2];
    const float* lora_down = (const float*)d_in[3];
    const float* lora_up   = (const float*)d_in[4];
    const float* smooth    = (const float*)d_in[5];
    const float* bias      = (const float*)d_in[6];
    float* out = (float*)d_out;

    char*  xq     = (char*)d_ws;                            // 256 KB packed
    float* ascale = (float*)((char*)d_ws + 262144);         // 16 KB
    float* t_part = (float*)((char*)d_ws + 262144 + 16384); // 128 KB (16 slices)

    quant_lora_kernel<<<B_DIM * 16, 256, 0, stream>>>(x, smooth, lora_down,
                                                      xq, ascale, t_part);
    main_fused_kernel<<<NT_DIM, 256, 0, stream>>>(q_w, wscales, (const v4i*)xq,
                                                  ascale, t_part, lora_up, bias, out);
}

// Round 7
// 297.716 us; speedup vs baseline: 1.3158x; 1.3158x over previous
//
#include <hip/hip_runtime.h>
#include <hip/hip_bf16.h>

#define K_DIM 4096
#define N_DIM 12288
#define B_DIM 64
#define G_DIM 64          // K / 64 groups
#define R_DIM 32
#define NT_DIM 768        // N / 16 n-tiles

typedef int v4i __attribute__((ext_vector_type(4)));

__device__ __forceinline__ int pack4(const v4i a) {
    return (a.x & 255) | ((a.y & 255) << 8) | ((a.z & 255) << 16) | (a.w << 24);
}

// ---------------------------------------------------------------------------
// Kernel 1: fused quantize + lora-down partial (R6 version — kept).
// Grid = B*16 blocks = (token b, k-chunk kc of 256). 256 threads.
//  - phase A: xd = x/smooth (one value/thread, shared via LDS); per-group
//    (64 consecutive threads = one wave = one group) absmax shuffle-reduce,
//    int4 quantize, write xq in MFMA-lane-packed layout
//    xq_p[bt][g][quad*16+(b&15)][16B]. rintf == jnp.round (half-even).
//  - phase B: lora partial: r = tid&31, c = tid>>5 sums 32 k's from LDS,
//    8->1 LDS reduce, write t_part[kc][b][r]  (disjoint slices -> no atomic,
//    no zero-init needed).
// ---------------------------------------------------------------------------
__global__ __launch_bounds__(256) void quant_lora_kernel(
    const float* __restrict__ x, const float* __restrict__ smooth,
    const float* __restrict__ ld, char* __restrict__ xq_p,
    float* __restrict__ ascale, float* __restrict__ t_part) {
    const int b = blockIdx.x >> 4;
    const int kc = blockIdx.x & 15;
    const int tid = threadIdx.x;
    const int k = kc * 256 + tid;

    __shared__ float sx[256];
    __shared__ float red[256];

    const float xd = x[b * K_DIM + k] / smooth[k];
    sx[tid] = xd;

    // --- quant (wave == group) ---
    const int lane = tid & 63;
    float a = fabsf(xd);
    #pragma unroll
    for (int off = 32; off; off >>= 1) a = fmaxf(a, __shfl_xor(a, off));
    const float as = fmaxf(a / 7.0f, 1e-8f);
    float q = rintf(xd / as);
    q = fminf(fmaxf(q, -8.0f), 7.0f);
    const int g = kc * 4 + (tid >> 6);
    const int bt = b >> 4, b15 = b & 15;
    const int quad = lane >> 4, kin = lane & 15;
    xq_p[((((size_t)bt * G_DIM + g) * 64) + quad * 16 + b15) * 16 + kin] = (char)(int)q;
    if (lane == 0) ascale[b * G_DIM + g] = as;
    __syncthreads();

    // --- lora-down partial over this 256-k chunk ---
    const int r = tid & 31, c = tid >> 5;     // c = 0..7
    const int kb = kc * 256 + c * 32;
    float acc = 0.f;
    #pragma unroll 8
    for (int kk = 0; kk < 32; ++kk)
        acc += sx[c * 32 + kk] * ld[(size_t)(kb + kk) * R_DIM + r];
    red[tid] = acc;
    __syncthreads();
    if (tid < 32) {
        float s = 0.f;
        #pragma unroll
        for (int c2 = 0; c2 < 8; ++c2) s += red[c2 * 32 + tid];
        t_part[kc * (B_DIM * R_DIM) + b * R_DIM + tid] = s;
    }
}

// ---------------------------------------------------------------------------
// Kernel 2: fused main — R5 structure (4-group chunks; VGPR-safe), t_part
// epilogue from R6. Grid = 768 blocks (one 16-col n-tile), 4 waves; wave w
// owns b-tile w -> no cross-wave reduction. 3 blocks/CU.
// K-loop: 16 chunks x 4 groups, double-buffered LDS staging of q_w:
//   staging: thread (srow=t>>4, scol=t&15) reads 4x dwordx4 from q_w row
//   n0+srow (per instr, wave = 4x 256 B contiguous segments, every byte
//   used), packs int32->int8x4 (16 VGPRs held), writes LDS rows stride
//   272 B. Loads for chunk j+1 issue before compute(j); pack after.
//   compute: per group ds_read_b128 bq + coalesced 1 KB/wave xa load (L2)
//   + mfma_i32_16x16x64_i8 + 4 scale-FMAs.
// NOTE R6 post-mortem: 8-group chunks (qa[8]) pushed VGPR to 256 -> 112 MB
// scratch spill traffic + occupancy 2 blocks/CU -> 185 us. Keep qa[4].
// ---------------------------------------------------------------------------
__global__ __launch_bounds__(256) void main_fused_kernel(
    const int* __restrict__ qw, const float* __restrict__ wscales,
    const v4i* __restrict__ xq_p, const float* __restrict__ ascale,
    const float* __restrict__ t_part, const float* __restrict__ lora_up,
    const float* __restrict__ bias, float* __restrict__ out) {
    __shared__ float s_ws[G_DIM * 16];      // [g][j]   4 KB
    __shared__ float s_as[G_DIM * 68];      // [g][b]  17 KB (pad 68)
    __shared__ float s_t[B_DIM * R_DIM];    // [b][r]   8 KB
    __shared__ int   s_qp[2][1088];         // 2 x (16 rows x 272 B) packed

    const int nt = blockIdx.x;
    const int n0 = nt * 16;
    const int tid = threadIdx.x;

    // staging-role indices
    const int srow = tid >> 4;              // 0..15  (n-row within tile)
    const int scol = tid & 15;              // 0..15  (4-int32 col group)
    const int* gptr = qw + (size_t)(n0 + srow) * K_DIM + scol * 4;

    // one-time LDS stages
    for (int i = tid; i < G_DIM * 16; i += 256)
        s_ws[i] = wscales[(i >> 4) * N_DIM + n0 + (i & 15)];
    for (int i = tid; i < B_DIM * G_DIM; i += 256) {
        const int b = i >> 6, g = i & 63;
        s_as[g * 68 + b] = ascale[i];
    }
    for (int i = tid; i < B_DIM * R_DIM; i += 256) {
        float s = 0.f;
        #pragma unroll
        for (int kc = 0; kc < 16; ++kc) s += t_part[kc * (B_DIM * R_DIM) + i];
        s_t[i] = s;
    }

    // stage chunk 0
    {
        v4i qa[4];
        #pragma unroll
        for (int i = 0; i < 4; ++i) qa[i] = *(const v4i*)(gptr + i * 64);
        #pragma unroll
        for (int i = 0; i < 4; ++i)
            s_qp[0][srow * 68 + i * 16 + scol] = pack4(qa[i]);
    }
    __syncthreads();

    const int w = tid >> 6, lane = tid & 63;
    const int col = lane & 15, quad = lane >> 4;

    float facc[4] = {0.f, 0.f, 0.f, 0.f};
    const v4i zero = {0, 0, 0, 0};
    const v4i* xbase = xq_p + (size_t)w * G_DIM * 64 + lane;
    const char* rdbase0 = (const char*)&s_qp[0][0] + col * 272 + quad * 16;
    const char* rdbase1 = (const char*)&s_qp[1][0] + col * 272 + quad * 16;

    #pragma unroll 2
    for (int j = 0; j < 16; ++j) {
        // issue loads for chunk j+1 (consumed only in the pack below)
        v4i qa[4];
        if (j < 15) {
            const int* p = gptr + (j + 1) * 256;
            #pragma unroll
            for (int i = 0; i < 4; ++i) qa[i] = *(const v4i*)(p + i * 64);
        }
        // compute chunk j
        const char* rd = (j & 1) ? rdbase1 : rdbase0;
        #pragma unroll
        for (int gi = 0; gi < 4; ++gi) {
            const int g = j * 4 + gi;
            const v4i bq = *(const v4i*)(rd + gi * 64);
            const v4i xa = xbase[(size_t)g * 64];
            const v4i d = __builtin_amdgcn_mfma_i32_16x16x64_i8(xa, bq, zero, 0, 0, 0);
            const float wsc = s_ws[g * 16 + col];
            const float4 as4 = *(const float4*)&s_as[g * 68 + w * 16 + quad * 4];
            facc[0] = fmaf(as4.x * wsc, (float)d[0], facc[0]);
            facc[1] = fmaf(as4.y * wsc, (float)d[1], facc[1]);
            facc[2] = fmaf(as4.z * wsc, (float)d[2], facc[2]);
            facc[3] = fmaf(as4.w * wsc, (float)d[3], facc[3]);
        }
        // pack + write chunk j+1 into the other buffer
        if (j < 15) {
            int* wb = (j & 1) ? &s_qp[0][0] : &s_qp[1][0];
            #pragma unroll
            for (int i = 0; i < 4; ++i)
                wb[srow * 68 + i * 16 + scol] = pack4(qa[i]);
        }
        __syncthreads();
    }

    // ---- epilogue: bias + rank-32 lora, direct store ----
    const int n = n0 + col;
    float4 lu[8];
    {
        const float4* lp = (const float4*)(lora_up + (size_t)n * R_DIM);
        #pragma unroll
        for (int i = 0; i < 8; ++i) lu[i] = lp[i];
    }
    const float bs = bias[n];
    #pragma unroll
    for (int r = 0; r < 4; ++r) {
        const int b = w * 16 + quad * 4 + r;
        float acc = facc[r] + bs;
        #pragma unroll
        for (int r2 = 0; r2 < 8; ++r2) {
            const float4 tv = *(const float4*)&s_t[b * R_DIM + r2 * 4];
            acc += tv.x * lu[r2].x + tv.y * lu[r2].y +
                   tv.z * lu[r2].z + tv.w * lu[r2].w;
        }
        out[(size_t)b * N_DIM + n] = acc;
    }
}

// ---------------------------------------------------------------------------
extern "C" void kernel_launch(void* const* d_in, const int* in_sizes, int n_in,
                              void* d_out, int out_size, void* d_ws, size_t ws_size,
                              hipStream_t stream) {
    const float* x         = (const float*)d_in[0];
    const int*   q_w       = (const int*)d_in[1];
    const float* wscales   = (const float*)d_in[2];
    const float* lora_down = (const float*)d_in[3];
    const float* lora_up   = (const float*)d_in[4];
    const float* smooth    = (const float*)d_in[5];
    const float* bias      = (const float*)d_in[6];
    float* out = (float*)d_out;

    char*  xq     = (char*)d_ws;                            // 256 KB packed
    float* ascale = (float*)((char*)d_ws + 262144);         // 16 KB
    float* t_part = (float*)((char*)d_ws + 262144 + 16384); // 128 KB (16 slices)

    quant_lora_kernel<<<B_DIM * 16, 256, 0, stream>>>(x, smooth, lora_down,
                                                      xq, ascale, t_part);
    main_fused_kernel<<<NT_DIM, 256, 0, stream>>>(q_w, wscales, (const v4i*)xq,
                                                  ascale, t_part, lora_up, bias, out);
}